// Round 1
// baseline (2676.141 us; speedup 1.0000x reference)
//
#include <hip/hip_runtime.h>
#include <hip/hip_bf16.h>
#include <math.h>

#define T_TOK 4096
#define HID   2560
#define NEXP  32
#define KTOP  6
#define FF    1536
#define SFF   3072
#define MAXP  (T_TOK*KTOP)

typedef __attribute__((ext_vector_type(8))) short short8;
typedef __attribute__((ext_vector_type(4))) float f32x4;

static __device__ __forceinline__ unsigned short f2bf(float x){
  return __builtin_bit_cast(unsigned short, (__bf16)x);
}
static __device__ __forceinline__ unsigned int pk2bf(float a, float b){
  return (unsigned int)f2bf(a) | ((unsigned int)f2bf(b) << 16);
}

// ---------------- cast hidden fp32 -> bf16 ----------------
__global__ void k_cast_x(const float* __restrict__ x, unsigned short* __restrict__ xb){
  int i = (blockIdx.x * 256 + threadIdx.x) * 4;
  float4 v = *(const float4*)(x + i);
  ushort4 o;
  o.x = f2bf(v.x); o.y = f2bf(v.y); o.z = f2bf(v.z); o.w = f2bf(v.w);
  *(ushort4*)(xb + i) = o;
}

// ---------------- router: logits -> softmax -> +bias -> top6 -> renorm ----------------
__global__ void k_router(const float* __restrict__ x, const float* __restrict__ rw,
                         const float* __restrict__ rb, float* __restrict__ top_w,
                         int* __restrict__ top_i, int* __restrict__ counts){
  const int lane = threadIdx.x & 63;
  const int wv   = threadIdx.x >> 6;
  const int t    = blockIdx.x * 4 + wv;
  const float* xr = x + (size_t)t * HID;
  float xv[40];
#pragma unroll
  for (int i = 0; i < 40; ++i) xv[i] = xr[lane + 64*i];
  float sc[32];
  for (int e = 0; e < 32; ++e){
    const float* w = rw + (size_t)e * HID;
    float s = 0.f;
#pragma unroll
    for (int i = 0; i < 40; ++i) s = fmaf(xv[i], w[lane + 64*i], s);
#pragma unroll
    for (int o = 32; o; o >>= 1) s += __shfl_xor(s, o);
    sc[e] = s;
  }
  float mx = sc[0];
#pragma unroll
  for (int e = 1; e < 32; ++e) mx = fmaxf(mx, sc[e]);
  float se = 0.f;
#pragma unroll
  for (int e = 0; e < 32; ++e){ sc[e] = expf(sc[e] - mx); se += sc[e]; }
  const float inv = 1.f / se;
#pragma unroll
  for (int e = 0; e < 32; ++e) sc[e] = sc[e] * inv + rb[e];

  unsigned chosen = 0; float swv[KTOP]; int sid[KTOP]; float wsum = 0.f;
#pragma unroll
  for (int k = 0; k < KTOP; ++k){
    float bv = -1e30f; int bi = 0;
#pragma unroll
    for (int e = 0; e < 32; ++e){
      bool ok = !((chosen >> e) & 1u);
      if (ok && sc[e] > bv){ bv = sc[e]; bi = e; }
    }
    chosen |= 1u << bi; swv[k] = bv; sid[k] = bi; wsum += bv;
  }
  const float dn = fmaxf(wsum, 1e-12f);
  if (lane < KTOP){
    top_w[t*KTOP + lane] = swv[lane] / dn;
    top_i[t*KTOP + lane] = sid[lane];
    atomicAdd(counts + sid[lane], 1);
  }
}

__global__ void k_scan(const int* __restrict__ counts, int* __restrict__ offsets){
  if (threadIdx.x == 0){
    int a = 0;
    for (int e = 0; e < NEXP; ++e){ offsets[e] = a; a += counts[e]; }
    offsets[NEXP] = a;
  }
}

__global__ void k_scatter(const int* __restrict__ top_i, const float* __restrict__ top_w,
                          const int* __restrict__ offsets, int* __restrict__ cursor,
                          int* __restrict__ pair_tok, float* __restrict__ pair_w){
  const int t = blockIdx.x * 256 + threadIdx.x;
  if (t >= T_TOK) return;
#pragma unroll
  for (int k = 0; k < KTOP; ++k){
    int e = top_i[t*KTOP + k];
    int pos = offsets[e] + atomicAdd(cursor + e, 1);
    pair_tok[pos] = t;
    pair_w[pos]   = top_w[t*KTOP + k];
  }
}

// ---------------- fused gate+up GEMM + SwiGLU -> bf16 act ----------------
// A: bf16 [rows][HID]; Wg/Wu: fp32 [HID][N] (k-major); out: bf16 [rows][N]
template<bool EXP>
__global__ __launch_bounds__(256)
void k_gateup(const unsigned short* __restrict__ A,
              const float* __restrict__ Wg, const float* __restrict__ Wu,
              unsigned short* __restrict__ outp,
              const int* __restrict__ pair_tok,
              const int* __restrict__ counts, const int* __restrict__ offsets,
              const int N)
{
  constexpr int K = HID;
  int M, base; const float *Bg, *Bu;
  if (EXP){
    const int e = blockIdx.z;
    M = counts[e]; base = offsets[e];
    const size_t wo = (size_t)e * K * (size_t)N;
    Bg = Wg + wo; Bu = Wu + wo;
  } else { M = T_TOK; base = 0; Bg = Wg; Bu = Wu; }
  const int mt = blockIdx.y;
  if (mt * 128 >= M) return;
  const int n0 = blockIdx.x * 128;

  __shared__ unsigned short Asm[128][40];
  __shared__ unsigned short Bgs[128][40];
  __shared__ unsigned short Bus[128][40];

  const int tid = threadIdx.x;
  const int lane = tid & 63;
  const int wv = tid >> 6;
  const int wr = wv >> 1, wc = wv & 1;

  const int ar = tid >> 2, aq = tid & 3;
  const unsigned short* asrc[2];
#pragma unroll
  for (int h = 0; h < 2; ++h){
    int rr = mt*128 + ar + 64*h;
    int rc = min(rr, M - 1);
    int row = EXP ? pair_tok[base + rc] : rc;
    asrc[h] = A + (size_t)row * K;
  }
  const int bn = tid & 127, bk4 = (tid >> 7) * 4;

  const f32x4 zero = {0.f, 0.f, 0.f, 0.f};
  f32x4 accg[4][4], accu[4][4];
#pragma unroll
  for (int m = 0; m < 4; ++m)
#pragma unroll
    for (int n = 0; n < 4; ++n){ accg[m][n] = zero; accu[m][n] = zero; }

  for (int k0 = 0; k0 < K; k0 += 32){
    __syncthreads();
#pragma unroll
    for (int h = 0; h < 2; ++h)
      *(uint4*)(&Asm[ar + 64*h][8*aq]) = *(const uint4*)(asrc[h] + k0 + 8*aq);
#pragma unroll
    for (int rd = 0; rd < 4; ++rd){
      const int kk = rd*8 + bk4;
      const float* g1 = Bg + (size_t)(k0 + kk) * N + n0 + bn;
      const float* g2 = Bu + (size_t)(k0 + kk) * N + n0 + bn;
      uint2 pg, pu;
      { float a0 = g1[0], a1 = g1[(size_t)N], a2 = g1[2*(size_t)N], a3 = g1[3*(size_t)N];
        pg.x = pk2bf(a0, a1); pg.y = pk2bf(a2, a3); }
      { float a0 = g2[0], a1 = g2[(size_t)N], a2 = g2[2*(size_t)N], a3 = g2[3*(size_t)N];
        pu.x = pk2bf(a0, a1); pu.y = pk2bf(a2, a3); }
      *(uint2*)(&Bgs[bn][kk]) = pg;
      *(uint2*)(&Bus[bn][kk]) = pu;
    }
    __syncthreads();

    short8 af[4], bg[4], bu[4];
    const int arow = wr*64 + (lane & 15);
    const int brow = wc*64 + (lane & 15);
    const int ko = (lane >> 4) * 8;
#pragma unroll
    for (int m = 0; m < 4; ++m) af[m] = *(const short8*)(&Asm[arow + m*16][ko]);
#pragma unroll
    for (int n = 0; n < 4; ++n){
      bg[n] = *(const short8*)(&Bgs[brow + n*16][ko]);
      bu[n] = *(const short8*)(&Bus[brow + n*16][ko]);
    }
#pragma unroll
    for (int m = 0; m < 4; ++m)
#pragma unroll
      for (int n = 0; n < 4; ++n){
        accg[m][n] = __builtin_amdgcn_mfma_f32_16x16x32_bf16(af[m], bg[n], accg[m][n], 0, 0, 0);
        accu[m][n] = __builtin_amdgcn_mfma_f32_16x16x32_bf16(af[m], bu[n], accu[m][n], 0, 0, 0);
      }
  }

#pragma unroll
  for (int m = 0; m < 4; ++m)
#pragma unroll
    for (int j = 0; j < 4; ++j){
      const int rr = mt*128 + wr*64 + m*16 + (lane >> 4)*4 + j;
      if (rr < M){
        unsigned short* orow = outp + (size_t)(base + rr) * N + n0 + wc*64 + (lane & 15);
#pragma unroll
        for (int n = 0; n < 4; ++n){
          float g = accg[m][n][j], u = accu[m][n][j];
          float s = (g / (1.f + expf(-g))) * u;   // silu(g)*u
          orow[n*16] = f2bf(s);
        }
      }
    }
}

// ---------------- down GEMM: act/s_act (bf16) x Wd (fp32) -> out fp32 ----------------
template<bool EXP>
__global__ __launch_bounds__(256)
void k_down(const unsigned short* __restrict__ A, const int K,
            const float* __restrict__ Wd, float* __restrict__ outp,
            const int* __restrict__ pair_tok, const float* __restrict__ pair_w,
            const int* __restrict__ counts, const int* __restrict__ offsets)
{
  constexpr int N = HID;
  int M, base; const float* Bw;
  if (EXP){
    const int e = blockIdx.z;
    M = counts[e]; base = offsets[e];
    Bw = Wd + (size_t)e * FF * HID;
  } else { M = T_TOK; base = 0; Bw = Wd; }
  const int mt = blockIdx.y;
  if (mt * 128 >= M) return;
  const int n0 = blockIdx.x * 128;

  __shared__ unsigned short Asm[128][40];
  __shared__ unsigned short Bs[128][40];

  const int tid = threadIdx.x;
  const int lane = tid & 63;
  const int wv = tid >> 6;
  const int wr = wv >> 1, wc = wv & 1;

  const int ar = tid >> 2, aq = tid & 3;
  const unsigned short* asrc[2];
#pragma unroll
  for (int h = 0; h < 2; ++h){
    int rr = mt*128 + ar + 64*h;
    int rc = min(rr, M - 1);
    asrc[h] = A + (size_t)(base + rc) * K;
  }
  const int bn = tid & 127, bk4 = (tid >> 7) * 4;

  const f32x4 zero = {0.f, 0.f, 0.f, 0.f};
  f32x4 acc[4][4];
#pragma unroll
  for (int m = 0; m < 4; ++m)
#pragma unroll
    for (int n = 0; n < 4; ++n) acc[m][n] = zero;

  for (int k0 = 0; k0 < K; k0 += 32){
    __syncthreads();
#pragma unroll
    for (int h = 0; h < 2; ++h)
      *(uint4*)(&Asm[ar + 64*h][8*aq]) = *(const uint4*)(asrc[h] + k0 + 8*aq);
#pragma unroll
    for (int rd = 0; rd < 4; ++rd){
      const int kk = rd*8 + bk4;
      const float* g1 = Bw + (size_t)(k0 + kk) * N + n0 + bn;
      uint2 pb;
      float a0 = g1[0], a1 = g1[(size_t)N], a2 = g1[2*(size_t)N], a3 = g1[3*(size_t)N];
      pb.x = pk2bf(a0, a1); pb.y = pk2bf(a2, a3);
      *(uint2*)(&Bs[bn][kk]) = pb;
    }
    __syncthreads();

    short8 af[4], bf[4];
    const int arow = wr*64 + (lane & 15);
    const int brow = wc*64 + (lane & 15);
    const int ko = (lane >> 4) * 8;
#pragma unroll
    for (int m = 0; m < 4; ++m) af[m] = *(const short8*)(&Asm[arow + m*16][ko]);
#pragma unroll
    for (int n = 0; n < 4; ++n) bf[n] = *(const short8*)(&Bs[brow + n*16][ko]);
#pragma unroll
    for (int m = 0; m < 4; ++m)
#pragma unroll
      for (int n = 0; n < 4; ++n)
        acc[m][n] = __builtin_amdgcn_mfma_f32_16x16x32_bf16(af[m], bf[n], acc[m][n], 0, 0, 0);
  }

#pragma unroll
  for (int m = 0; m < 4; ++m)
#pragma unroll
    for (int j = 0; j < 4; ++j){
      const int rr = mt*128 + wr*64 + m*16 + (lane >> 4)*4 + j;
      if (rr < M){
        if (EXP){
          const int p = base + rr;
          const int tok = pair_tok[p];
          const float pw = pair_w[p];
          float* orow = outp + (size_t)tok * HID + n0 + wc*64 + (lane & 15);
#pragma unroll
          for (int n = 0; n < 4; ++n) atomicAdd(orow + n*16, acc[m][n][j] * pw);
        } else {
          float* orow = outp + (size_t)rr * HID + n0 + wc*64 + (lane & 15);
#pragma unroll
          for (int n = 0; n < 4; ++n) orow[n*16] = acc[m][n][j];
        }
      }
    }
}

extern "C" void kernel_launch(void* const* d_in, const int* in_sizes, int n_in,
                              void* d_out, int out_size, void* d_ws, size_t ws_size,
                              hipStream_t stream)
{
  (void)in_sizes; (void)n_in; (void)out_size; (void)ws_size;
  const float* hid = (const float*)d_in[0];
  const float* rw  = (const float*)d_in[1];
  const float* rb  = (const float*)d_in[2];
  const float* gw  = (const float*)d_in[3];
  const float* uw  = (const float*)d_in[4];
  const float* dw  = (const float*)d_in[5];
  const float* sgw = (const float*)d_in[6];
  const float* suw = (const float*)d_in[7];
  const float* sdw = (const float*)d_in[8];
  float* out = (float*)d_out;

  char* ws = (char*)d_ws;
  size_t o = 0;
  unsigned short* xb   = (unsigned short*)(ws + o); o += (size_t)T_TOK*HID*2;
  unsigned short* act  = (unsigned short*)(ws + o); o += (size_t)MAXP*FF*2;
  unsigned short* sact = (unsigned short*)(ws + o); o += (size_t)T_TOK*SFF*2;
  float* top_w    = (float*)(ws + o); o += (size_t)T_TOK*KTOP*4;
  int*   top_i    = (int*)(ws + o);   o += (size_t)T_TOK*KTOP*4;
  float* pair_w   = (float*)(ws + o); o += (size_t)MAXP*4;
  int*   pair_tok = (int*)(ws + o);   o += (size_t)MAXP*4;
  int*   counts   = (int*)(ws + o);   o += NEXP*4;
  int*   offsets  = (int*)(ws + o);   o += (NEXP+1)*4;
  int*   cursor   = (int*)(ws + o);   o += NEXP*4;

  hipMemsetAsync(counts, 0, (NEXP + (NEXP+1) + NEXP) * sizeof(int), stream);

  k_cast_x<<<(T_TOK*HID)/1024, 256, 0, stream>>>(hid, xb);
  k_router<<<T_TOK/4, 256, 0, stream>>>(hid, rw, rb, top_w, top_i, counts);
  k_scan<<<1, 64, 0, stream>>>(counts, offsets);
  k_scatter<<<T_TOK/256, 256, 0, stream>>>(top_i, top_w, offsets, cursor, pair_tok, pair_w);

  k_gateup<true><<<dim3(FF/128, T_TOK/128, NEXP), 256, 0, stream>>>(
      xb, gw, uw, act, pair_tok, counts, offsets, FF);
  k_gateup<false><<<dim3(SFF/128, T_TOK/128, 1), 256, 0, stream>>>(
      xb, sgw, suw, sact, nullptr, nullptr, nullptr, SFF);
  k_down<false><<<dim3(HID/128, T_TOK/128, 1), 256, 0, stream>>>(
      sact, SFF, sdw, out, nullptr, nullptr, nullptr, nullptr);
  k_down<true><<<dim3(HID/128, T_TOK/128, NEXP), 256, 0, stream>>>(
      act, FF, dw, out, pair_tok, pair_w, counts, offsets);
}

// Round 2
// 2537.657 us; speedup vs baseline: 1.0546x; 1.0546x over previous
//
#include <hip/hip_runtime.h>
#include <hip/hip_bf16.h>
#include <math.h>

#define T_TOK 4096
#define HID   2560
#define NEXP  32
#define KTOP  6
#define FF    1536
#define SFF   3072
#define MAXP  (T_TOK*KTOP)

typedef __attribute__((ext_vector_type(8))) short short8;
typedef __attribute__((ext_vector_type(4))) float f32x4;

static __device__ __forceinline__ unsigned short f2bf(float x){
  return __builtin_bit_cast(unsigned short, (__bf16)x);
}

static __device__ __forceinline__ void gload_lds16(const void* g, void* l){
  __builtin_amdgcn_global_load_lds(
      (const __attribute__((address_space(1))) unsigned int*)g,
      (__attribute__((address_space(3))) unsigned int*)l, 16, 0, 0);
}

// ---------------- cast hidden fp32 -> bf16 ----------------
__global__ void k_cast_x(const float* __restrict__ x, unsigned short* __restrict__ xb){
  int i = (blockIdx.x * 256 + threadIdx.x) * 4;
  float4 v = *(const float4*)(x + i);
  ushort4 o;
  o.x = f2bf(v.x); o.y = f2bf(v.y); o.z = f2bf(v.z); o.w = f2bf(v.w);
  *(ushort4*)(xb + i) = o;
}

// ---------------- transpose + convert: fp32 [R][C] -> bf16 [C][R] ----------------
__global__ __launch_bounds__(256)
void k_transpose(const float* __restrict__ in, unsigned short* __restrict__ out,
                 const int R, const int C){
  const size_t bo = (size_t)blockIdx.z * (size_t)R * C;
  __shared__ unsigned short t2[64][68];
  const int r0 = blockIdx.y * 64, c0 = blockIdx.x * 64;
  const int tid = threadIdx.x;
  const int cr = tid & 15;   // col group (x4 floats)
  const int rr = tid >> 4;   // 0..15
#pragma unroll
  for (int i = 0; i < 4; ++i){
    const int r = rr + 16*i;
    float4 v = *(const float4*)(in + bo + (size_t)(r0 + r)*C + c0 + cr*4);
    ushort4 p;
    p.x = f2bf(v.x); p.y = f2bf(v.y); p.z = f2bf(v.z); p.w = f2bf(v.w);
    *(ushort4*)(&t2[r][cr*4]) = p;
  }
  __syncthreads();
  const int rw = tid & 7;    // 8 chunks of 8 shorts along r
  const int ro = tid >> 3;   // 0..31
#pragma unroll
  for (int i = 0; i < 2; ++i){
    const int c = ro + 32*i;
    ushort4 a, b;
    a.x = t2[rw*8+0][c]; a.y = t2[rw*8+1][c]; a.z = t2[rw*8+2][c]; a.w = t2[rw*8+3][c];
    b.x = t2[rw*8+4][c]; b.y = t2[rw*8+5][c]; b.z = t2[rw*8+6][c]; b.w = t2[rw*8+7][c];
    unsigned short* op = out + bo + (size_t)(c0 + c)*R + r0 + rw*8;
    *(ushort4*)(op)     = a;
    *(ushort4*)(op + 4) = b;
  }
}

// ---------------- router ----------------
__global__ void k_router(const float* __restrict__ x, const float* __restrict__ rw,
                         const float* __restrict__ rb, float* __restrict__ top_w,
                         int* __restrict__ top_i, int* __restrict__ counts){
  const int lane = threadIdx.x & 63;
  const int wv   = threadIdx.x >> 6;
  const int t    = blockIdx.x * 4 + wv;
  const float* xr = x + (size_t)t * HID;
  float xv[40];
#pragma unroll
  for (int i = 0; i < 40; ++i) xv[i] = xr[lane + 64*i];
  float sc[32];
  for (int e = 0; e < 32; ++e){
    const float* w = rw + (size_t)e * HID;
    float s = 0.f;
#pragma unroll
    for (int i = 0; i < 40; ++i) s = fmaf(xv[i], w[lane + 64*i], s);
#pragma unroll
    for (int o = 32; o; o >>= 1) s += __shfl_xor(s, o);
    sc[e] = s;
  }
  float mx = sc[0];
#pragma unroll
  for (int e = 1; e < 32; ++e) mx = fmaxf(mx, sc[e]);
  float se = 0.f;
#pragma unroll
  for (int e = 0; e < 32; ++e){ sc[e] = expf(sc[e] - mx); se += sc[e]; }
  const float inv = 1.f / se;
#pragma unroll
  for (int e = 0; e < 32; ++e) sc[e] = sc[e] * inv + rb[e];

  unsigned chosen = 0; float swv[KTOP]; int sid[KTOP]; float wsum = 0.f;
#pragma unroll
  for (int k = 0; k < KTOP; ++k){
    float bv = -1e30f; int bi = 0;
#pragma unroll
    for (int e = 0; e < 32; ++e){
      bool ok = !((chosen >> e) & 1u);
      if (ok && sc[e] > bv){ bv = sc[e]; bi = e; }
    }
    chosen |= 1u << bi; swv[k] = bv; sid[k] = bi; wsum += bv;
  }
  const float dn = fmaxf(wsum, 1e-12f);
  if (lane < KTOP){
    top_w[t*KTOP + lane] = swv[lane] / dn;
    top_i[t*KTOP + lane] = sid[lane];
    atomicAdd(counts + sid[lane], 1);
  }
}

__global__ void k_scan(const int* __restrict__ counts, int* __restrict__ offsets){
  if (threadIdx.x == 0){
    int a = 0;
    for (int e = 0; e < NEXP; ++e){ offsets[e] = a; a += counts[e]; }
    offsets[NEXP] = a;
  }
}

__global__ void k_scatter(const int* __restrict__ top_i, const float* __restrict__ top_w,
                          const int* __restrict__ offsets, int* __restrict__ cursor,
                          int* __restrict__ pair_tok, float* __restrict__ pair_w){
  const int t = blockIdx.x * 256 + threadIdx.x;
  if (t >= T_TOK) return;
#pragma unroll
  for (int k = 0; k < KTOP; ++k){
    int e = top_i[t*KTOP + k];
    int pos = offsets[e] + atomicAdd(cursor + e, 1);
    pair_tok[pos] = t;
    pair_w[pos]   = top_w[t*KTOP + k];
  }
}

// ---------------- fused gate+up GEMM + SwiGLU (m97 structure) ----------------
// A: bf16 [rows][K=HID]; BgT/BuT: bf16 [N][K] (n-major, k-contig); out: bf16 [rows][N]
template<bool EXP>
__global__ __launch_bounds__(256)
void k_gateup2(const unsigned short* __restrict__ A,
               const unsigned short* __restrict__ BgT,
               const unsigned short* __restrict__ BuT,
               unsigned short* __restrict__ outp,
               const int* __restrict__ pair_tok,
               const int* __restrict__ counts, const int* __restrict__ offsets,
               const int N)
{
  constexpr int K = HID;
  int M, base; const unsigned short *Bg, *Bu;
  if (EXP){
    const int e = blockIdx.z;
    M = counts[e]; base = offsets[e];
    const size_t wo = (size_t)e * (size_t)N * K;
    Bg = BgT + wo; Bu = BuT + wo;
  } else { M = T_TOK; base = 0; Bg = BgT; Bu = BuT; }
  const int mt = blockIdx.y;
  if (mt * 128 >= M) return;
  const int n0 = blockIdx.x * 128;

  __shared__ unsigned short As[128*32];
  __shared__ unsigned short Bgs[128*32];
  __shared__ unsigned short Bus[128*32];

  const int tid  = threadIdx.x;
  const int lane = tid & 63;
  const int w    = tid >> 6;
  const int wr = w >> 1, wc = w & 1;

  // staging: per wave 2 issues x 16B/lane per tile; lane covers (row = w*32+i*16+lane/4, chunk = lane%4)
  const int lrow  = lane >> 2;
  const int chunk = lane & 3;
  const unsigned short *aptr[2], *bgptr[2], *buptr[2];
  int sw[2];
#pragma unroll
  for (int i = 0; i < 2; ++i){
    const int r = w*32 + i*16 + lrow;            // tile-local row 0..127
    sw[i] = (chunk ^ (r & 3)) * 8;               // swizzled element offset (inverse-swz source)
    int ar = min(mt*128 + r, M - 1);
    int arow = EXP ? pair_tok[base + ar] : ar;
    aptr[i]  = A  + (size_t)arow * K;
    bgptr[i] = Bg + (size_t)(n0 + r) * K;
    buptr[i] = Bu + (size_t)(n0 + r) * K;
  }
  char* asd = (char*)As  + w*2048;
  char* bgd = (char*)Bgs + w*2048;
  char* bud = (char*)Bus + w*2048;

  const f32x4 zero = {0.f,0.f,0.f,0.f};
  f32x4 accg[4][4], accu[4][4];
#pragma unroll
  for (int m = 0; m < 4; ++m)
#pragma unroll
    for (int n = 0; n < 4; ++n){ accg[m][n] = zero; accu[m][n] = zero; }

  const int am  = wr*64 + (lane & 15);
  const int bn_ = wc*64 + (lane & 15);
  const int fg  = ((lane >> 4) ^ (lane & 3)) * 16;   // swizzled chunk byte offset

  for (int k0 = 0; k0 < K; k0 += 32){
    __syncthreads();
#pragma unroll
    for (int i = 0; i < 2; ++i){
      gload_lds16(aptr[i]  + k0 + sw[i], asd + i*1024);
      gload_lds16(bgptr[i] + k0 + sw[i], bgd + i*1024);
      gload_lds16(buptr[i] + k0 + sw[i], bud + i*1024);
    }
    __syncthreads();
    short8 af[4], bgf[4], buf_[4];
#pragma unroll
    for (int m = 0; m < 4; ++m)
      af[m] = *(const short8*)((const char*)As + (am + m*16)*64 + fg);
#pragma unroll
    for (int n = 0; n < 4; ++n){
      bgf[n]  = *(const short8*)((const char*)Bgs + (bn_ + n*16)*64 + fg);
      buf_[n] = *(const short8*)((const char*)Bus + (bn_ + n*16)*64 + fg);
    }
#pragma unroll
    for (int m = 0; m < 4; ++m)
#pragma unroll
      for (int n = 0; n < 4; ++n){
        accg[m][n] = __builtin_amdgcn_mfma_f32_16x16x32_bf16(af[m], bgf[n],  accg[m][n], 0, 0, 0);
        accu[m][n] = __builtin_amdgcn_mfma_f32_16x16x32_bf16(af[m], buf_[n], accu[m][n], 0, 0, 0);
      }
  }

#pragma unroll
  for (int m = 0; m < 4; ++m)
#pragma unroll
    for (int j = 0; j < 4; ++j){
      const int rr = mt*128 + wr*64 + m*16 + (lane >> 4)*4 + j;
      if (rr < M){
        unsigned short* orow = outp + (size_t)(base + rr) * N + n0 + wc*64 + (lane & 15);
#pragma unroll
        for (int n = 0; n < 4; ++n){
          float g = accg[m][n][j], u = accu[m][n][j];
          float s = (g / (1.f + expf(-g))) * u;
          orow[n*16] = f2bf(s);
        }
      }
    }
}

// ---------------- down GEMM (m97 structure): act bf16 x BT bf16 [N=HID][K] -> fp32 ----------------
template<bool EXP>
__global__ __launch_bounds__(256)
void k_down2(const unsigned short* __restrict__ Aact, const int K,
             const unsigned short* __restrict__ BT, float* __restrict__ outp,
             const int* __restrict__ pair_tok, const float* __restrict__ pair_w,
             const int* __restrict__ counts, const int* __restrict__ offsets)
{
  constexpr int N = HID;
  int M, base; const unsigned short* Bw;
  if (EXP){
    const int e = blockIdx.z;
    M = counts[e]; base = offsets[e];
    Bw = BT + (size_t)e * (size_t)N * K;
  } else { M = T_TOK; base = 0; Bw = BT; }
  const int mt = blockIdx.y;
  if (mt * 128 >= M) return;
  const int n0 = blockIdx.x * 128;

  __shared__ unsigned short As[128*32];
  __shared__ unsigned short Bs[128*32];

  const int tid  = threadIdx.x;
  const int lane = tid & 63;
  const int w    = tid >> 6;
  const int wr = w >> 1, wc = w & 1;

  const int lrow  = lane >> 2;
  const int chunk = lane & 3;
  const unsigned short *aptr[2], *bptr[2];
  int sw[2];
#pragma unroll
  for (int i = 0; i < 2; ++i){
    const int r = w*32 + i*16 + lrow;
    sw[i] = (chunk ^ (r & 3)) * 8;
    int ar = min(mt*128 + r, M - 1);
    aptr[i] = Aact + (size_t)(base + ar) * K;
    bptr[i] = Bw + (size_t)(n0 + r) * K;
  }
  char* asd = (char*)As + w*2048;
  char* bsd = (char*)Bs + w*2048;

  const f32x4 zero = {0.f,0.f,0.f,0.f};
  f32x4 acc[4][4];
#pragma unroll
  for (int m = 0; m < 4; ++m)
#pragma unroll
    for (int n = 0; n < 4; ++n) acc[m][n] = zero;

  const int am  = wr*64 + (lane & 15);
  const int bn_ = wc*64 + (lane & 15);
  const int fg  = ((lane >> 4) ^ (lane & 3)) * 16;

  for (int k0 = 0; k0 < K; k0 += 32){
    __syncthreads();
#pragma unroll
    for (int i = 0; i < 2; ++i){
      gload_lds16(aptr[i] + k0 + sw[i], asd + i*1024);
      gload_lds16(bptr[i] + k0 + sw[i], bsd + i*1024);
    }
    __syncthreads();
    short8 af[4], bf_[4];
#pragma unroll
    for (int m = 0; m < 4; ++m)
      af[m] = *(const short8*)((const char*)As + (am + m*16)*64 + fg);
#pragma unroll
    for (int n = 0; n < 4; ++n)
      bf_[n] = *(const short8*)((const char*)Bs + (bn_ + n*16)*64 + fg);
#pragma unroll
    for (int m = 0; m < 4; ++m)
#pragma unroll
      for (int n = 0; n < 4; ++n)
        acc[m][n] = __builtin_amdgcn_mfma_f32_16x16x32_bf16(af[m], bf_[n], acc[m][n], 0, 0, 0);
  }

#pragma unroll
  for (int m = 0; m < 4; ++m)
#pragma unroll
    for (int j = 0; j < 4; ++j){
      const int rr = mt*128 + wr*64 + m*16 + (lane >> 4)*4 + j;
      if (rr < M){
        if (EXP){
          const int p = base + rr;
          const int tok = pair_tok[p];
          const float pw = pair_w[p];
          float* orow = outp + (size_t)tok * HID + n0 + wc*64 + (lane & 15);
#pragma unroll
          for (int n = 0; n < 4; ++n) atomicAdd(orow + n*16, acc[m][n][j] * pw);
        } else {
          float* orow = outp + (size_t)rr * HID + n0 + wc*64 + (lane & 15);
#pragma unroll
          for (int n = 0; n < 4; ++n) orow[n*16] = acc[m][n][j];
        }
      }
    }
}

extern "C" void kernel_launch(void* const* d_in, const int* in_sizes, int n_in,
                              void* d_out, int out_size, void* d_ws, size_t ws_size,
                              hipStream_t stream)
{
  (void)in_sizes; (void)n_in; (void)out_size; (void)ws_size;
  const float* hid = (const float*)d_in[0];
  const float* rw  = (const float*)d_in[1];
  const float* rb  = (const float*)d_in[2];
  const float* gw  = (const float*)d_in[3];
  const float* uw  = (const float*)d_in[4];
  const float* dw  = (const float*)d_in[5];
  const float* sgw = (const float*)d_in[6];
  const float* suw = (const float*)d_in[7];
  const float* sdw = (const float*)d_in[8];
  float* out = (float*)d_out;

  char* ws = (char*)d_ws;
  size_t o = 0;
  unsigned short* xb   = (unsigned short*)(ws + o); o += (size_t)T_TOK*HID*2;     // 21 MB
  unsigned short* act  = (unsigned short*)(ws + o); o += (size_t)MAXP*FF*2;       // 75.5 MB
  unsigned short* sact = (unsigned short*)(ws + o); o += (size_t)T_TOK*SFF*2;     // 25 MB
  // weight region, phased reuse:
  unsigned short* Wbuf = (unsigned short*)(ws + o);
  unsigned short* gT  = Wbuf;                                   // [32][F][H]
  unsigned short* uT  = Wbuf + (size_t)NEXP*FF*HID;             // [32][F][H]
  unsigned short* sgT = Wbuf + (size_t)2*NEXP*FF*HID;           // [SF][H]
  unsigned short* suT = sgT + (size_t)SFF*HID;                  // [SF][H]
  unsigned short* dT  = Wbuf;                                   // [32][H][F] (reuses gT)
  unsigned short* sdT = Wbuf + (size_t)NEXP*FF*HID;             // [H][SF]   (reuses uT)
  o += (size_t)2*NEXP*FF*HID*2 + (size_t)2*SFF*HID*2;           // 535 MB
  float* top_w    = (float*)(ws + o); o += (size_t)T_TOK*KTOP*4;
  int*   top_i    = (int*)(ws + o);   o += (size_t)T_TOK*KTOP*4;
  float* pair_w   = (float*)(ws + o); o += (size_t)MAXP*4;
  int*   pair_tok = (int*)(ws + o);   o += (size_t)MAXP*4;
  int*   counts   = (int*)(ws + o);   o += NEXP*4;
  int*   offsets  = (int*)(ws + o);   o += (NEXP+1)*4;
  int*   cursor   = (int*)(ws + o);   o += NEXP*4;

  hipMemsetAsync(counts, 0, (NEXP + (NEXP+1) + NEXP) * sizeof(int), stream);

  k_cast_x<<<(T_TOK*HID)/1024, 256, 0, stream>>>(hid, xb);
  k_router<<<T_TOK/4, 256, 0, stream>>>(hid, rw, rb, top_w, top_i, counts);
  k_scan<<<1, 64, 0, stream>>>(counts, offsets);
  k_scatter<<<T_TOK/256, 256, 0, stream>>>(top_i, top_w, offsets, cursor, pair_tok, pair_w);

  // phase A transposes: gate/up (expert + shared)
  k_transpose<<<dim3(FF/64,  HID/64, NEXP), 256, 0, stream>>>(gw,  gT,  HID, FF);
  k_transpose<<<dim3(FF/64,  HID/64, NEXP), 256, 0, stream>>>(uw,  uT,  HID, FF);
  k_transpose<<<dim3(SFF/64, HID/64, 1),    256, 0, stream>>>(sgw, sgT, HID, SFF);
  k_transpose<<<dim3(SFF/64, HID/64, 1),    256, 0, stream>>>(suw, suT, HID, SFF);

  k_gateup2<true><<<dim3(FF/128, T_TOK/128, NEXP), 256, 0, stream>>>(
      xb, gT, uT, act, pair_tok, counts, offsets, FF);
  k_gateup2<false><<<dim3(SFF/128, T_TOK/128, 1), 256, 0, stream>>>(
      xb, sgT, suT, sact, nullptr, nullptr, nullptr, SFF);

  // phase B transposes: down (reuse gate/up region)
  k_transpose<<<dim3(HID/64, FF/64,  NEXP), 256, 0, stream>>>(dw,  dT,  FF,  HID);
  k_transpose<<<dim3(HID/64, SFF/64, 1),    256, 0, stream>>>(sdw, sdT, SFF, HID);

  k_down2<false><<<dim3(HID/128, T_TOK/128, 1), 256, 0, stream>>>(
      sact, SFF, sdT, out, nullptr, nullptr, nullptr, nullptr);
  k_down2<true><<<dim3(HID/128, T_TOK/128, NEXP), 256, 0, stream>>>(
      act, FF, dT, out, pair_tok, pair_w, counts, offsets);
}

// Round 3
// 2225.405 us; speedup vs baseline: 1.2025x; 1.1403x over previous
//
#include <hip/hip_runtime.h>
#include <hip/hip_bf16.h>
#include <math.h>

#define T_TOK 4096
#define HID   2560
#define NEXP  32
#define KTOP  6
#define FF    1536
#define SFF   3072
#define MAXP  (T_TOK*KTOP)

typedef __attribute__((ext_vector_type(8))) short short8;
typedef __attribute__((ext_vector_type(4))) float f32x4;

static __device__ __forceinline__ unsigned short f2bf(float x){
  return __builtin_bit_cast(unsigned short, (__bf16)x);
}

static __device__ __forceinline__ void gload_lds16(const void* g, void* l){
  __builtin_amdgcn_global_load_lds(
      (const __attribute__((address_space(1))) unsigned int*)g,
      (__attribute__((address_space(3))) unsigned int*)l, 16, 0, 0);
}

// ---------------- cast hidden fp32 -> bf16 ----------------
__global__ void k_cast_x(const float* __restrict__ x, unsigned short* __restrict__ xb){
  int i = (blockIdx.x * 256 + threadIdx.x) * 4;
  float4 v = *(const float4*)(x + i);
  ushort4 o;
  o.x = f2bf(v.x); o.y = f2bf(v.y); o.z = f2bf(v.z); o.w = f2bf(v.w);
  *(ushort4*)(xb + i) = o;
}

// ---------------- transpose + convert: fp32 [R][C] -> bf16 [C][R] ----------------
__global__ __launch_bounds__(256)
void k_transpose(const float* __restrict__ in, unsigned short* __restrict__ out,
                 const int R, const int C){
  const size_t bo = (size_t)blockIdx.z * (size_t)R * C;
  __shared__ unsigned short t2[64][68];
  const int r0 = blockIdx.y * 64, c0 = blockIdx.x * 64;
  const int tid = threadIdx.x;
  const int cr = tid & 15;   // col group (x4 floats)
  const int rr = tid >> 4;   // 0..15
#pragma unroll
  for (int i = 0; i < 4; ++i){
    const int r = rr + 16*i;
    float4 v = *(const float4*)(in + bo + (size_t)(r0 + r)*C + c0 + cr*4);
    ushort4 p;
    p.x = f2bf(v.x); p.y = f2bf(v.y); p.z = f2bf(v.z); p.w = f2bf(v.w);
    *(ushort4*)(&t2[r][cr*4]) = p;
  }
  __syncthreads();
  const int rw = tid & 7;    // 8 chunks of 8 shorts along r
  const int ro = tid >> 3;   // 0..31
#pragma unroll
  for (int i = 0; i < 2; ++i){
    const int c = ro + 32*i;
    ushort4 a, b;
    a.x = t2[rw*8+0][c]; a.y = t2[rw*8+1][c]; a.z = t2[rw*8+2][c]; a.w = t2[rw*8+3][c];
    b.x = t2[rw*8+4][c]; b.y = t2[rw*8+5][c]; b.z = t2[rw*8+6][c]; b.w = t2[rw*8+7][c];
    unsigned short* op = out + bo + (size_t)(c0 + c)*R + r0 + rw*8;
    *(ushort4*)(op)     = a;
    *(ushort4*)(op + 4) = b;
  }
}

// ---------------- router ----------------
__global__ void k_router(const float* __restrict__ x, const float* __restrict__ rw,
                         const float* __restrict__ rb, float* __restrict__ top_w,
                         int* __restrict__ top_i, int* __restrict__ counts){
  const int lane = threadIdx.x & 63;
  const int wv   = threadIdx.x >> 6;
  const int t    = blockIdx.x * 4 + wv;
  const float* xr = x + (size_t)t * HID;
  float xv[40];
#pragma unroll
  for (int i = 0; i < 40; ++i) xv[i] = xr[lane + 64*i];
  float sc[32];
  for (int e = 0; e < 32; ++e){
    const float* w = rw + (size_t)e * HID;
    float s = 0.f;
#pragma unroll
    for (int i = 0; i < 40; ++i) s = fmaf(xv[i], w[lane + 64*i], s);
#pragma unroll
    for (int o = 32; o; o >>= 1) s += __shfl_xor(s, o);
    sc[e] = s;
  }
  float mx = sc[0];
#pragma unroll
  for (int e = 1; e < 32; ++e) mx = fmaxf(mx, sc[e]);
  float se = 0.f;
#pragma unroll
  for (int e = 0; e < 32; ++e){ sc[e] = expf(sc[e] - mx); se += sc[e]; }
  const float inv = 1.f / se;
#pragma unroll
  for (int e = 0; e < 32; ++e) sc[e] = sc[e] * inv + rb[e];

  unsigned chosen = 0; float swv[KTOP]; int sid[KTOP]; float wsum = 0.f;
#pragma unroll
  for (int k = 0; k < KTOP; ++k){
    float bv = -1e30f; int bi = 0;
#pragma unroll
    for (int e = 0; e < 32; ++e){
      bool ok = !((chosen >> e) & 1u);
      if (ok && sc[e] > bv){ bv = sc[e]; bi = e; }
    }
    chosen |= 1u << bi; swv[k] = bv; sid[k] = bi; wsum += bv;
  }
  const float dn = fmaxf(wsum, 1e-12f);
  if (lane < KTOP){
    top_w[t*KTOP + lane] = swv[lane] / dn;
    top_i[t*KTOP + lane] = sid[lane];
    atomicAdd(counts + sid[lane], 1);
  }
}

__global__ void k_scan(const int* __restrict__ counts, int* __restrict__ offsets){
  if (threadIdx.x == 0){
    int a = 0;
    for (int e = 0; e < NEXP; ++e){ offsets[e] = a; a += counts[e]; }
    offsets[NEXP] = a;
  }
}

__global__ void k_scatter(const int* __restrict__ top_i, const float* __restrict__ top_w,
                          const int* __restrict__ offsets, int* __restrict__ cursor,
                          int* __restrict__ pair_tok, float* __restrict__ pair_w){
  const int t = blockIdx.x * 256 + threadIdx.x;
  if (t >= T_TOK) return;
#pragma unroll
  for (int k = 0; k < KTOP; ++k){
    int e = top_i[t*KTOP + k];
    int pos = offsets[e] + atomicAdd(cursor + e, 1);
    pair_tok[pos] = t;
    pair_w[pos]   = top_w[t*KTOP + k];
  }
}

// ---------------- fused gate+up GEMM + SwiGLU, double-buffered pipeline ----------------
// A: bf16 [rows][K=HID]; BgT/BuT: bf16 [N][K]; out: bf16 [rows][N]
template<bool EXP>
__global__ __launch_bounds__(256, 3)
void k_gateup2(const unsigned short* __restrict__ A,
               const unsigned short* __restrict__ BgT,
               const unsigned short* __restrict__ BuT,
               unsigned short* __restrict__ outp,
               const int* __restrict__ pair_tok,
               const int* __restrict__ counts, const int* __restrict__ offsets,
               const int N)
{
  constexpr int K = HID;
  constexpr int NT = K / 32;
  int M, base; const unsigned short *Bg, *Bu;
  if (EXP){
    const int e = blockIdx.z;
    M = counts[e]; base = offsets[e];
    const size_t wo = (size_t)e * (size_t)N * K;
    Bg = BgT + wo; Bu = BuT + wo;
  } else { M = T_TOK; base = 0; Bg = BgT; Bu = BuT; }
  const int mt = blockIdx.y;
  if (mt * 128 >= M) return;
  const int n0 = blockIdx.x * 128;

  __shared__ unsigned short As[2][128*32];
  __shared__ unsigned short Bgs[2][128*32];
  __shared__ unsigned short Bus[2][128*32];

  const int tid  = threadIdx.x;
  const int lane = tid & 63;
  const int w    = tid >> 6;
  const int wr = w >> 1, wc = w & 1;

  const int lrow  = lane >> 2;
  const int chunk = lane & 3;
  const unsigned short *aptr[2], *bgptr[2], *buptr[2];
  int sw[2];
#pragma unroll
  for (int i = 0; i < 2; ++i){
    const int r = w*32 + i*16 + lrow;            // tile-local row 0..127
    sw[i] = (chunk ^ (r & 3)) * 8;               // inverse-swz source offset (elements)
    int ar = min(mt*128 + r, M - 1);
    int arow = EXP ? pair_tok[base + ar] : ar;
    aptr[i]  = A  + (size_t)arow * K;
    bgptr[i] = Bg + (size_t)(n0 + r) * K;
    buptr[i] = Bu + (size_t)(n0 + r) * K;
  }

  const f32x4 zero = {0.f,0.f,0.f,0.f};
  f32x4 accg[4][4], accu[4][4];
#pragma unroll
  for (int m = 0; m < 4; ++m)
#pragma unroll
    for (int n = 0; n < 4; ++n){ accg[m][n] = zero; accu[m][n] = zero; }

  const int am  = wr*64 + (lane & 15);
  const int bn_ = wc*64 + (lane & 15);
  const int fg  = ((lane >> 4) ^ (lane & 3)) * 16;   // swizzled chunk byte offset

#define GU_STAGE(cb, k0)                                                   \
  {                                                                        \
    char* asd = (char*)As[cb]  + w*2048;                                   \
    char* bgd = (char*)Bgs[cb] + w*2048;                                   \
    char* bud = (char*)Bus[cb] + w*2048;                                   \
    _Pragma("unroll")                                                      \
    for (int i = 0; i < 2; ++i){                                           \
      gload_lds16(aptr[i]  + (k0) + sw[i], asd + i*1024);                  \
      gload_lds16(bgptr[i] + (k0) + sw[i], bgd + i*1024);                  \
      gload_lds16(buptr[i] + (k0) + sw[i], bud + i*1024);                  \
    }                                                                      \
  }

  GU_STAGE(0, 0)
  __syncthreads();
  int cur = 0;
  for (int t = 0; t < NT; ++t){
    if (t + 1 < NT) GU_STAGE(cur ^ 1, (t + 1) * 32)
    short8 af[4], bgf[4], buf_[4];
#pragma unroll
    for (int m = 0; m < 4; ++m)
      af[m] = *(const short8*)((const char*)As[cur] + (am + m*16)*64 + fg);
#pragma unroll
    for (int n = 0; n < 4; ++n){
      bgf[n]  = *(const short8*)((const char*)Bgs[cur] + (bn_ + n*16)*64 + fg);
      buf_[n] = *(const short8*)((const char*)Bus[cur] + (bn_ + n*16)*64 + fg);
    }
#pragma unroll
    for (int m = 0; m < 4; ++m)
#pragma unroll
      for (int n = 0; n < 4; ++n){
        accg[m][n] = __builtin_amdgcn_mfma_f32_16x16x32_bf16(af[m], bgf[n],  accg[m][n], 0, 0, 0);
        accu[m][n] = __builtin_amdgcn_mfma_f32_16x16x32_bf16(af[m], buf_[n], accu[m][n], 0, 0, 0);
      }
    __syncthreads();   // drains this iter's prefetch (after MFMA) + read/write fence
    cur ^= 1;
  }
#undef GU_STAGE

#pragma unroll
  for (int m = 0; m < 4; ++m)
#pragma unroll
    for (int j = 0; j < 4; ++j){
      const int rr = mt*128 + wr*64 + m*16 + (lane >> 4)*4 + j;
      if (rr < M){
        unsigned short* orow = outp + (size_t)(base + rr) * N + n0 + wc*64 + (lane & 15);
#pragma unroll
        for (int n = 0; n < 4; ++n){
          float g = accg[m][n][j], u = accu[m][n][j];
          float s = (g / (1.f + expf(-g))) * u;
          orow[n*16] = f2bf(s);
        }
      }
    }
}

// ---------------- down GEMM, double-buffered pipeline ----------------
template<bool EXP>
__global__ __launch_bounds__(256, 4)
void k_down2(const unsigned short* __restrict__ Aact, const int K,
             const unsigned short* __restrict__ BT, float* __restrict__ outp,
             const int* __restrict__ pair_tok, const float* __restrict__ pair_w,
             const int* __restrict__ counts, const int* __restrict__ offsets)
{
  constexpr int N = HID;
  int M, base; const unsigned short* Bw;
  if (EXP){
    const int e = blockIdx.z;
    M = counts[e]; base = offsets[e];
    Bw = BT + (size_t)e * (size_t)N * K;
  } else { M = T_TOK; base = 0; Bw = BT; }
  const int mt = blockIdx.y;
  if (mt * 128 >= M) return;
  const int n0 = blockIdx.x * 128;

  __shared__ unsigned short As[2][128*32];
  __shared__ unsigned short Bs[2][128*32];

  const int tid  = threadIdx.x;
  const int lane = tid & 63;
  const int w    = tid >> 6;
  const int wr = w >> 1, wc = w & 1;

  const int lrow  = lane >> 2;
  const int chunk = lane & 3;
  const unsigned short *aptr[2], *bptr[2];
  int sw[2];
#pragma unroll
  for (int i = 0; i < 2; ++i){
    const int r = w*32 + i*16 + lrow;
    sw[i] = (chunk ^ (r & 3)) * 8;
    int ar = min(mt*128 + r, M - 1);
    aptr[i] = Aact + (size_t)(base + ar) * K;
    bptr[i] = Bw + (size_t)(n0 + r) * K;
  }

  const f32x4 zero = {0.f,0.f,0.f,0.f};
  f32x4 acc[4][4];
#pragma unroll
  for (int m = 0; m < 4; ++m)
#pragma unroll
    for (int n = 0; n < 4; ++n) acc[m][n] = zero;

  const int am  = wr*64 + (lane & 15);
  const int bn_ = wc*64 + (lane & 15);
  const int fg  = ((lane >> 4) ^ (lane & 3)) * 16;

#define DN_STAGE(cb, k0)                                                   \
  {                                                                        \
    char* asd = (char*)As[cb] + w*2048;                                    \
    char* bsd = (char*)Bs[cb] + w*2048;                                    \
    _Pragma("unroll")                                                      \
    for (int i = 0; i < 2; ++i){                                           \
      gload_lds16(aptr[i] + (k0) + sw[i], asd + i*1024);                   \
      gload_lds16(bptr[i] + (k0) + sw[i], bsd + i*1024);                   \
    }                                                                      \
  }

  const int NT = K / 32;
  DN_STAGE(0, 0)
  __syncthreads();
  int cur = 0;
  for (int t = 0; t < NT; ++t){
    if (t + 1 < NT) DN_STAGE(cur ^ 1, (t + 1) * 32)
    short8 af[4], bf_[4];
#pragma unroll
    for (int m = 0; m < 4; ++m)
      af[m] = *(const short8*)((const char*)As[cur] + (am + m*16)*64 + fg);
#pragma unroll
    for (int n = 0; n < 4; ++n)
      bf_[n] = *(const short8*)((const char*)Bs[cur] + (bn_ + n*16)*64 + fg);
#pragma unroll
    for (int m = 0; m < 4; ++m)
#pragma unroll
      for (int n = 0; n < 4; ++n)
        acc[m][n] = __builtin_amdgcn_mfma_f32_16x16x32_bf16(af[m], bf_[n], acc[m][n], 0, 0, 0);
    __syncthreads();
    cur ^= 1;
  }
#undef DN_STAGE

#pragma unroll
  for (int m = 0; m < 4; ++m)
#pragma unroll
    for (int j = 0; j < 4; ++j){
      const int rr = mt*128 + wr*64 + m*16 + (lane >> 4)*4 + j;
      if (rr < M){
        if (EXP){
          const int p = base + rr;
          const int tok = pair_tok[p];
          const float pw = pair_w[p];
          float* orow = outp + (size_t)tok * HID + n0 + wc*64 + (lane & 15);
#pragma unroll
          for (int n = 0; n < 4; ++n) atomicAdd(orow + n*16, acc[m][n][j] * pw);
        } else {
          float* orow = outp + (size_t)rr * HID + n0 + wc*64 + (lane & 15);
#pragma unroll
          for (int n = 0; n < 4; ++n) orow[n*16] = acc[m][n][j];
        }
      }
    }
}

extern "C" void kernel_launch(void* const* d_in, const int* in_sizes, int n_in,
                              void* d_out, int out_size, void* d_ws, size_t ws_size,
                              hipStream_t stream)
{
  (void)in_sizes; (void)n_in; (void)out_size; (void)ws_size;
  const float* hid = (const float*)d_in[0];
  const float* rw  = (const float*)d_in[1];
  const float* rb  = (const float*)d_in[2];
  const float* gw  = (const float*)d_in[3];
  const float* uw  = (const float*)d_in[4];
  const float* dw  = (const float*)d_in[5];
  const float* sgw = (const float*)d_in[6];
  const float* suw = (const float*)d_in[7];
  const float* sdw = (const float*)d_in[8];
  float* out = (float*)d_out;

  char* ws = (char*)d_ws;
  size_t o = 0;
  unsigned short* xb   = (unsigned short*)(ws + o); o += (size_t)T_TOK*HID*2;     // 21 MB
  unsigned short* act  = (unsigned short*)(ws + o); o += (size_t)MAXP*FF*2;       // 75.5 MB
  unsigned short* sact = (unsigned short*)(ws + o); o += (size_t)T_TOK*SFF*2;     // 25 MB
  // weight region, phased reuse:
  unsigned short* Wbuf = (unsigned short*)(ws + o);
  unsigned short* gT  = Wbuf;                                   // [32][F][H]
  unsigned short* uT  = Wbuf + (size_t)NEXP*FF*HID;             // [32][F][H]
  unsigned short* sgT = Wbuf + (size_t)2*NEXP*FF*HID;           // [SF][H]
  unsigned short* suT = sgT + (size_t)SFF*HID;                  // [SF][H]
  unsigned short* dT  = Wbuf;                                   // [32][H][F] (reuses gT)
  unsigned short* sdT = Wbuf + (size_t)NEXP*FF*HID;             // [H][SF]   (reuses uT)
  o += (size_t)2*NEXP*FF*HID*2 + (size_t)2*SFF*HID*2;           // 535 MB
  float* top_w    = (float*)(ws + o); o += (size_t)T_TOK*KTOP*4;
  int*   top_i    = (int*)(ws + o);   o += (size_t)T_TOK*KTOP*4;
  float* pair_w   = (float*)(ws + o); o += (size_t)MAXP*4;
  int*   pair_tok = (int*)(ws + o);   o += (size_t)MAXP*4;
  int*   counts   = (int*)(ws + o);   o += NEXP*4;
  int*   offsets  = (int*)(ws + o);   o += (NEXP+1)*4;
  int*   cursor   = (int*)(ws + o);   o += NEXP*4;

  hipMemsetAsync(counts, 0, (NEXP + (NEXP+1) + NEXP) * sizeof(int), stream);

  k_cast_x<<<(T_TOK*HID)/1024, 256, 0, stream>>>(hid, xb);
  k_router<<<T_TOK/4, 256, 0, stream>>>(hid, rw, rb, top_w, top_i, counts);
  k_scan<<<1, 64, 0, stream>>>(counts, offsets);
  k_scatter<<<T_TOK/256, 256, 0, stream>>>(top_i, top_w, offsets, cursor, pair_tok, pair_w);

  // phase A transposes: gate/up (expert + shared)
  k_transpose<<<dim3(FF/64,  HID/64, NEXP), 256, 0, stream>>>(gw,  gT,  HID, FF);
  k_transpose<<<dim3(FF/64,  HID/64, NEXP), 256, 0, stream>>>(uw,  uT,  HID, FF);
  k_transpose<<<dim3(SFF/64, HID/64, 1),    256, 0, stream>>>(sgw, sgT, HID, SFF);
  k_transpose<<<dim3(SFF/64, HID/64, 1),    256, 0, stream>>>(suw, suT, HID, SFF);

  k_gateup2<true><<<dim3(FF/128, T_TOK/128, NEXP), 256, 0, stream>>>(
      xb, gT, uT, act, pair_tok, counts, offsets, FF);
  k_gateup2<false><<<dim3(SFF/128, T_TOK/128, 1), 256, 0, stream>>>(
      xb, sgT, suT, sact, nullptr, nullptr, nullptr, SFF);

  // phase B transposes: down (reuse gate/up region)
  k_transpose<<<dim3(HID/64, FF/64,  NEXP), 256, 0, stream>>>(dw,  dT,  FF,  HID);
  k_transpose<<<dim3(HID/64, SFF/64, 1),    256, 0, stream>>>(sdw, sdT, SFF, HID);

  k_down2<false><<<dim3(HID/128, T_TOK/128, 1), 256, 0, stream>>>(
      sact, SFF, sdT, out, nullptr, nullptr, nullptr, nullptr);
  k_down2<true><<<dim3(HID/128, T_TOK/128, NEXP), 256, 0, stream>>>(
      act, FF, dT, out, pair_tok, pair_w, counts, offsets);
}

// Round 4
// 1952.945 us; speedup vs baseline: 1.3703x; 1.1395x over previous
//
#include <hip/hip_runtime.h>
#include <hip/hip_bf16.h>
#include <math.h>

#define T_TOK 4096
#define HID   2560
#define NEXP  32
#define KTOP  6
#define FF    1536
#define SFF   3072
#define MAXP  (T_TOK*KTOP)

typedef __attribute__((ext_vector_type(8))) short short8;
typedef __attribute__((ext_vector_type(4))) float f32x4;

static __device__ __forceinline__ unsigned short f2bf(float x){
  return __builtin_bit_cast(unsigned short, (__bf16)x);
}

static __device__ __forceinline__ void gload_lds16(const void* g, void* l){
  __builtin_amdgcn_global_load_lds(
      (const __attribute__((address_space(1))) unsigned int*)g,
      (__attribute__((address_space(3))) unsigned int*)l, 16, 0, 0);
}

// ---------------- cast hidden fp32 -> bf16 ----------------
__global__ void k_cast_x(const float* __restrict__ x, unsigned short* __restrict__ xb){
  int i = (blockIdx.x * 256 + threadIdx.x) * 4;
  float4 v = *(const float4*)(x + i);
  ushort4 o;
  o.x = f2bf(v.x); o.y = f2bf(v.y); o.z = f2bf(v.z); o.w = f2bf(v.w);
  *(ushort4*)(xb + i) = o;
}

// ---------------- transpose + convert: fp32 [R][C] -> bf16 [C][R] ----------------
__global__ __launch_bounds__(256)
void k_transpose(const float* __restrict__ in, unsigned short* __restrict__ out,
                 const int R, const int C){
  const size_t bo = (size_t)blockIdx.z * (size_t)R * C;
  __shared__ unsigned short t2[64][72];
  const int r0 = blockIdx.y * 64, c0 = blockIdx.x * 64;
  const int tid = threadIdx.x;
  const int cr = tid & 15;
  const int rr = tid >> 4;
#pragma unroll
  for (int i = 0; i < 4; ++i){
    const int r = rr + 16*i;
    float4 v = *(const float4*)(in + bo + (size_t)(r0 + r)*C + c0 + cr*4);
    ushort4 p;
    p.x = f2bf(v.x); p.y = f2bf(v.y); p.z = f2bf(v.z); p.w = f2bf(v.w);
    *(ushort4*)(&t2[r][cr*4]) = p;
  }
  __syncthreads();
  const int rw = tid & 7;
  const int ro = tid >> 3;
#pragma unroll
  for (int i = 0; i < 2; ++i){
    const int c = ro + 32*i;
    ushort4 a, b;
    a.x = t2[rw*8+0][c]; a.y = t2[rw*8+1][c]; a.z = t2[rw*8+2][c]; a.w = t2[rw*8+3][c];
    b.x = t2[rw*8+4][c]; b.y = t2[rw*8+5][c]; b.z = t2[rw*8+6][c]; b.w = t2[rw*8+7][c];
    unsigned short* op = out + bo + (size_t)(c0 + c)*R + r0 + rw*8;
    *(ushort4*)(op)     = a;
    *(ushort4*)(op + 4) = b;
  }
}

// ---------------- router ----------------
__global__ void k_router(const float* __restrict__ x, const float* __restrict__ rw,
                         const float* __restrict__ rb, float* __restrict__ top_w,
                         int* __restrict__ top_i, int* __restrict__ counts){
  const int lane = threadIdx.x & 63;
  const int wv   = threadIdx.x >> 6;
  const int t    = blockIdx.x * 4 + wv;
  const float* xr = x + (size_t)t * HID;
  float xv[40];
#pragma unroll
  for (int i = 0; i < 40; ++i) xv[i] = xr[lane + 64*i];
  float sc[32];
  for (int e = 0; e < 32; ++e){
    const float* w = rw + (size_t)e * HID;
    float s = 0.f;
#pragma unroll
    for (int i = 0; i < 40; ++i) s = fmaf(xv[i], w[lane + 64*i], s);
#pragma unroll
    for (int o = 32; o; o >>= 1) s += __shfl_xor(s, o);
    sc[e] = s;
  }
  float mx = sc[0];
#pragma unroll
  for (int e = 1; e < 32; ++e) mx = fmaxf(mx, sc[e]);
  float se = 0.f;
#pragma unroll
  for (int e = 0; e < 32; ++e){ sc[e] = expf(sc[e] - mx); se += sc[e]; }
  const float inv = 1.f / se;
#pragma unroll
  for (int e = 0; e < 32; ++e) sc[e] = sc[e] * inv + rb[e];

  unsigned chosen = 0; float swv[KTOP]; int sid[KTOP]; float wsum = 0.f;
#pragma unroll
  for (int k = 0; k < KTOP; ++k){
    float bv = -1e30f; int bi = 0;
#pragma unroll
    for (int e = 0; e < 32; ++e){
      bool ok = !((chosen >> e) & 1u);
      if (ok && sc[e] > bv){ bv = sc[e]; bi = e; }
    }
    chosen |= 1u << bi; swv[k] = bv; sid[k] = bi; wsum += bv;
  }
  const float dn = fmaxf(wsum, 1e-12f);
  if (lane < KTOP){
    top_w[t*KTOP + lane] = swv[lane] / dn;
    top_i[t*KTOP + lane] = sid[lane];
    atomicAdd(counts + sid[lane], 1);
  }
}

__global__ void k_scan(const int* __restrict__ counts, int* __restrict__ offsets){
  if (threadIdx.x == 0){
    int a = 0;
    for (int e = 0; e < NEXP; ++e){ offsets[e] = a; a += counts[e]; }
    offsets[NEXP] = a;
  }
}

__global__ void k_scatter(const int* __restrict__ top_i, const float* __restrict__ top_w,
                          const int* __restrict__ offsets, int* __restrict__ cursor,
                          int* __restrict__ pair_tok, float* __restrict__ pair_w){
  const int t = blockIdx.x * 256 + threadIdx.x;
  if (t >= T_TOK) return;
#pragma unroll
  for (int k = 0; k < KTOP; ++k){
    int e = top_i[t*KTOP + k];
    int pos = offsets[e] + atomicAdd(cursor + e, 1);
    pair_tok[pos] = t;
    pair_w[pos]   = top_w[t*KTOP + k];
  }
}

// ---------------- fused gate+up GEMM + SwiGLU, 3-buffer counted-vmcnt pipeline ----------------
// 1D grid, bijective XCD swizzle, logical order: e-major, n, m-fastest.
template<bool EXP>
__global__ __launch_bounds__(256, 2)
void k_gateup3(const unsigned short* __restrict__ A,
               const unsigned short* __restrict__ BgT,
               const unsigned short* __restrict__ BuT,
               unsigned short* __restrict__ outp,
               const int* __restrict__ pair_tok,
               const int* __restrict__ counts, const int* __restrict__ offsets,
               const int N)
{
  constexpr int K = HID;
  constexpr int NT = K / 32;
  const int total = gridDim.x;
  const int phys  = blockIdx.x;
  const int logical = (phys & 7) * (total >> 3) + (phys >> 3);
  const int mt   = logical & 31;              // T_TOK/128 = 32 m-tiles
  const int rest = logical >> 5;
  const int ntiles = N >> 7;
  const int n0 = (rest % ntiles) << 7;

  int M, base; const unsigned short *Bg, *Bu;
  if (EXP){
    const int e = rest / ntiles;
    M = counts[e]; base = offsets[e];
    const size_t wo = (size_t)e * (size_t)N * K;
    Bg = BgT + wo; Bu = BuT + wo;
  } else { M = T_TOK; base = 0; Bg = BgT; Bu = BuT; }
  if (mt * 128 >= M) return;

  __shared__ unsigned short As[3][4096];
  __shared__ unsigned short Bgs[3][4096];
  __shared__ unsigned short Bus[3][4096];

  const int tid  = threadIdx.x;
  const int lane = tid & 63;
  const int w    = tid >> 6;
  const int wr = w >> 1, wc = w & 1;

  const int lrow  = lane >> 2;
  const int chunk = lane & 3;
  const unsigned short *aptr[2], *bgptr[2], *buptr[2];
  int sw[2];
#pragma unroll
  for (int i = 0; i < 2; ++i){
    const int r = w*32 + i*16 + lrow;
    sw[i] = (chunk ^ (r & 3)) * 8;
    int ar = min(mt*128 + r, M - 1);
    int arow = EXP ? pair_tok[base + ar] : ar;
    aptr[i]  = A  + (size_t)arow * K;
    bgptr[i] = Bg + (size_t)(n0 + r) * K;
    buptr[i] = Bu + (size_t)(n0 + r) * K;
  }

  const f32x4 zero = {0.f,0.f,0.f,0.f};
  f32x4 accg[4][4], accu[4][4];
#pragma unroll
  for (int m = 0; m < 4; ++m)
#pragma unroll
    for (int n = 0; n < 4; ++n){ accg[m][n] = zero; accu[m][n] = zero; }

  const int am  = wr*64 + (lane & 15);
  const int bn_ = wc*64 + (lane & 15);
  const int fg  = ((lane >> 4) ^ (lane & 3)) * 16;

#define GU_STAGE(cb, k0)                                                   \
  {                                                                        \
    char* asd = (char*)As[cb]  + w*2048;                                   \
    char* bgd = (char*)Bgs[cb] + w*2048;                                   \
    char* bud = (char*)Bus[cb] + w*2048;                                   \
    _Pragma("unroll")                                                      \
    for (int i = 0; i < 2; ++i){                                           \
      gload_lds16(aptr[i]  + (k0) + sw[i], asd + i*1024);                  \
      gload_lds16(bgptr[i] + (k0) + sw[i], bgd + i*1024);                  \
      gload_lds16(buptr[i] + (k0) + sw[i], bud + i*1024);                  \
    }                                                                      \
  }

  GU_STAGE(0, 0)
  GU_STAGE(1, 32)
  asm volatile("s_waitcnt vmcnt(6)" ::: "memory");
  __builtin_amdgcn_s_barrier();

  int c0 = 0, c1 = 1, c2 = 2;
  for (int t = 0; t < NT; ++t){
    if (t + 2 < NT) GU_STAGE(c2, (t + 2) * 32)
    short8 af[4], bgf[4], buf_[4];
#pragma unroll
    for (int m = 0; m < 4; ++m)
      af[m] = *(const short8*)((const char*)As + c0*8192 + (am + m*16)*64 + fg);
#pragma unroll
    for (int n = 0; n < 4; ++n){
      bgf[n]  = *(const short8*)((const char*)Bgs + c0*8192 + (bn_ + n*16)*64 + fg);
      buf_[n] = *(const short8*)((const char*)Bus + c0*8192 + (bn_ + n*16)*64 + fg);
    }
#pragma unroll
    for (int m = 0; m < 4; ++m)
#pragma unroll
      for (int n = 0; n < 4; ++n){
        accg[m][n] = __builtin_amdgcn_mfma_f32_16x16x32_bf16(af[m], bgf[n],  accg[m][n], 0, 0, 0);
        accu[m][n] = __builtin_amdgcn_mfma_f32_16x16x32_bf16(af[m], buf_[n], accu[m][n], 0, 0, 0);
      }
    if (t + 2 < NT) asm volatile("s_waitcnt vmcnt(6)" ::: "memory");
    else            asm volatile("s_waitcnt vmcnt(0)" ::: "memory");
    __builtin_amdgcn_s_barrier();
    int tmp = c0; c0 = c1; c1 = c2; c2 = tmp;
  }
#undef GU_STAGE

#pragma unroll
  for (int m = 0; m < 4; ++m)
#pragma unroll
    for (int j = 0; j < 4; ++j){
      const int rr = mt*128 + wr*64 + m*16 + (lane >> 4)*4 + j;
      if (rr < M){
        unsigned short* orow = outp + (size_t)(base + rr) * N + n0 + wc*64 + (lane & 15);
#pragma unroll
        for (int n = 0; n < 4; ++n){
          float g = accg[m][n][j], u = accu[m][n][j];
          float s = (g / (1.f + expf(-g))) * u;
          orow[n*16] = f2bf(s);
        }
      }
    }
}

// ---------------- down GEMM, 3-buffer counted-vmcnt pipeline ----------------
template<bool EXP>
__global__ __launch_bounds__(256, 3)
void k_down3(const unsigned short* __restrict__ Aact, const int K,
             const unsigned short* __restrict__ BT, float* __restrict__ outp,
             const int* __restrict__ pair_tok, const float* __restrict__ pair_w,
             const int* __restrict__ counts, const int* __restrict__ offsets)
{
  constexpr int N = HID;
  constexpr int ntiles = N >> 7;                 // 20
  const int total = gridDim.x;
  const int phys  = blockIdx.x;
  const int logical = (phys & 7) * (total >> 3) + (phys >> 3);
  const int mt   = logical & 31;
  const int rest = logical >> 5;
  const int n0 = (rest % ntiles) << 7;

  int M, base; const unsigned short* Bw;
  if (EXP){
    const int e = rest / ntiles;
    M = counts[e]; base = offsets[e];
    Bw = BT + (size_t)e * (size_t)N * K;
  } else { M = T_TOK; base = 0; Bw = BT; }
  if (mt * 128 >= M) return;

  __shared__ unsigned short As[3][4096];
  __shared__ unsigned short Bs[3][4096];

  const int tid  = threadIdx.x;
  const int lane = tid & 63;
  const int w    = tid >> 6;
  const int wr = w >> 1, wc = w & 1;

  const int lrow  = lane >> 2;
  const int chunk = lane & 3;
  const unsigned short *aptr[2], *bptr[2];
  int sw[2];
#pragma unroll
  for (int i = 0; i < 2; ++i){
    const int r = w*32 + i*16 + lrow;
    sw[i] = (chunk ^ (r & 3)) * 8;
    int ar = min(mt*128 + r, M - 1);
    aptr[i] = Aact + (size_t)(base + ar) * K;
    bptr[i] = Bw + (size_t)(n0 + r) * K;
  }

  const f32x4 zero = {0.f,0.f,0.f,0.f};
  f32x4 acc[4][4];
#pragma unroll
  for (int m = 0; m < 4; ++m)
#pragma unroll
    for (int n = 0; n < 4; ++n) acc[m][n] = zero;

  const int am  = wr*64 + (lane & 15);
  const int bn_ = wc*64 + (lane & 15);
  const int fg  = ((lane >> 4) ^ (lane & 3)) * 16;

#define DN_STAGE(cb, k0)                                                   \
  {                                                                        \
    char* asd = (char*)As[cb] + w*2048;                                    \
    char* bsd = (char*)Bs[cb] + w*2048;                                    \
    _Pragma("unroll")                                                      \
    for (int i = 0; i < 2; ++i){                                           \
      gload_lds16(aptr[i] + (k0) + sw[i], asd + i*1024);                   \
      gload_lds16(bptr[i] + (k0) + sw[i], bsd + i*1024);                   \
    }                                                                      \
  }

  const int NT = K / 32;
  DN_STAGE(0, 0)
  DN_STAGE(1, 32)
  asm volatile("s_waitcnt vmcnt(4)" ::: "memory");
  __builtin_amdgcn_s_barrier();

  int c0 = 0, c1 = 1, c2 = 2;
  for (int t = 0; t < NT; ++t){
    if (t + 2 < NT) DN_STAGE(c2, (t + 2) * 32)
    short8 af[4], bf_[4];
#pragma unroll
    for (int m = 0; m < 4; ++m)
      af[m] = *(const short8*)((const char*)As + c0*8192 + (am + m*16)*64 + fg);
#pragma unroll
    for (int n = 0; n < 4; ++n)
      bf_[n] = *(const short8*)((const char*)Bs + c0*8192 + (bn_ + n*16)*64 + fg);
#pragma unroll
    for (int m = 0; m < 4; ++m)
#pragma unroll
      for (int n = 0; n < 4; ++n)
        acc[m][n] = __builtin_amdgcn_mfma_f32_16x16x32_bf16(af[m], bf_[n], acc[m][n], 0, 0, 0);
    if (t + 2 < NT) asm volatile("s_waitcnt vmcnt(4)" ::: "memory");
    else            asm volatile("s_waitcnt vmcnt(0)" ::: "memory");
    __builtin_amdgcn_s_barrier();
    int tmp = c0; c0 = c1; c1 = c2; c2 = tmp;
  }
#undef DN_STAGE

#pragma unroll
  for (int m = 0; m < 4; ++m)
#pragma unroll
    for (int j = 0; j < 4; ++j){
      const int rr = mt*128 + wr*64 + m*16 + (lane >> 4)*4 + j;
      if (rr < M){
        if (EXP){
          const int p = base + rr;
          const int tok = pair_tok[p];
          const float pw = pair_w[p];
          float* orow = outp + (size_t)tok * HID + n0 + wc*64 + (lane & 15);
#pragma unroll
          for (int n = 0; n < 4; ++n) atomicAdd(orow + n*16, acc[m][n][j] * pw);
        } else {
          float* orow = outp + (size_t)rr * HID + n0 + wc*64 + (lane & 15);
#pragma unroll
          for (int n = 0; n < 4; ++n) orow[n*16] = acc[m][n][j];
        }
      }
    }
}

extern "C" void kernel_launch(void* const* d_in, const int* in_sizes, int n_in,
                              void* d_out, int out_size, void* d_ws, size_t ws_size,
                              hipStream_t stream)
{
  (void)in_sizes; (void)n_in; (void)out_size; (void)ws_size;
  const float* hid = (const float*)d_in[0];
  const float* rw  = (const float*)d_in[1];
  const float* rb  = (const float*)d_in[2];
  const float* gw  = (const float*)d_in[3];
  const float* uw  = (const float*)d_in[4];
  const float* dw  = (const float*)d_in[5];
  const float* sgw = (const float*)d_in[6];
  const float* suw = (const float*)d_in[7];
  const float* sdw = (const float*)d_in[8];
  float* out = (float*)d_out;

  char* ws = (char*)d_ws;
  size_t o = 0;
  unsigned short* xb   = (unsigned short*)(ws + o); o += (size_t)T_TOK*HID*2;
  unsigned short* act  = (unsigned short*)(ws + o); o += (size_t)MAXP*FF*2;
  unsigned short* sact = (unsigned short*)(ws + o); o += (size_t)T_TOK*SFF*2;
  unsigned short* Wbuf = (unsigned short*)(ws + o);
  unsigned short* gT  = Wbuf;
  unsigned short* uT  = Wbuf + (size_t)NEXP*FF*HID;
  unsigned short* sgT = Wbuf + (size_t)2*NEXP*FF*HID;
  unsigned short* suT = sgT + (size_t)SFF*HID;
  unsigned short* dT  = Wbuf;
  unsigned short* sdT = Wbuf + (size_t)NEXP*FF*HID;
  o += (size_t)2*NEXP*FF*HID*2 + (size_t)2*SFF*HID*2;
  float* top_w    = (float*)(ws + o); o += (size_t)T_TOK*KTOP*4;
  int*   top_i    = (int*)(ws + o);   o += (size_t)T_TOK*KTOP*4;
  float* pair_w   = (float*)(ws + o); o += (size_t)MAXP*4;
  int*   pair_tok = (int*)(ws + o);   o += (size_t)MAXP*4;
  int*   counts   = (int*)(ws + o);   o += NEXP*4;
  int*   offsets  = (int*)(ws + o);   o += (NEXP+1)*4;
  int*   cursor   = (int*)(ws + o);   o += NEXP*4;

  hipMemsetAsync(counts, 0, (NEXP + (NEXP+1) + NEXP) * sizeof(int), stream);

  k_cast_x<<<(T_TOK*HID)/1024, 256, 0, stream>>>(hid, xb);
  k_router<<<T_TOK/4, 256, 0, stream>>>(hid, rw, rb, top_w, top_i, counts);
  k_scan<<<1, 64, 0, stream>>>(counts, offsets);
  k_scatter<<<T_TOK/256, 256, 0, stream>>>(top_i, top_w, offsets, cursor, pair_tok, pair_w);

  // phase A transposes: gate/up (expert + shared)
  k_transpose<<<dim3(FF/64,  HID/64, NEXP), 256, 0, stream>>>(gw,  gT,  HID, FF);
  k_transpose<<<dim3(FF/64,  HID/64, NEXP), 256, 0, stream>>>(uw,  uT,  HID, FF);
  k_transpose<<<dim3(SFF/64, HID/64, 1),    256, 0, stream>>>(sgw, sgT, HID, SFF);
  k_transpose<<<dim3(SFF/64, HID/64, 1),    256, 0, stream>>>(suw, suT, HID, SFF);

  // 1D grids, XCD-bijective swizzle inside kernel (total % 8 == 0 in all cases)
  k_gateup3<true><<<32*(FF/128)*NEXP, 256, 0, stream>>>(
      xb, gT, uT, act, pair_tok, counts, offsets, FF);
  k_gateup3<false><<<32*(SFF/128), 256, 0, stream>>>(
      xb, sgT, suT, sact, nullptr, nullptr, nullptr, SFF);

  // phase B transposes: down (reuse gate/up region)
  k_transpose<<<dim3(HID/64, FF/64,  NEXP), 256, 0, stream>>>(dw,  dT,  FF,  HID);
  k_transpose<<<dim3(HID/64, SFF/64, 1),    256, 0, stream>>>(sdw, sdT, SFF, HID);

  k_down3<false><<<32*(HID/128), 256, 0, stream>>>(
      sact, SFF, sdT, out, nullptr, nullptr, nullptr, nullptr);
  k_down3<true><<<32*(HID/128)*NEXP, 256, 0, stream>>>(
      act, FF, dT, out, pair_tok, pair_w, counts, offsets);
}